// Round 12
// baseline (2069.277 us; speedup 1.0000x reference)
//
#include <hip/hip_runtime.h>

// Wav2Vec BLSTM: 4-layer bi-LSTM (B=32, T=1000, H=32, G=128) + mean-pool + fc.
//
// Round 12:
//  GEMM rewritten: 128x128 tile, acc 8x8/thread (fma:ds = 64:4), staging
//  mapping row=tid>>1 / khalf=(tid&1)*16 -> LDS writes are 2-way (free) by
//  construction; prefetch next K-chunk into regs BEFORE compute (latency
//  hidden under ~4096cy of fma), single LDS buffer, 2 barriers/chunk.
//  LSTM reverted to round-10 verified version (staged lgkmcnt broadcast).

#define TB 1000
#define LOG2E 1.44269504088896340736f

typedef int   v2i __attribute__((ext_vector_type(2)));
typedef float v2f __attribute__((ext_vector_type(2)));

__device__ __forceinline__ float fexp2(float x) {
#if __has_builtin(__builtin_amdgcn_exp2f)
    return __builtin_amdgcn_exp2f(x);
#else
    return exp2f(x);
#endif
}

// returns v[lane ^ 32]; pickx precomputed per-lane (convention-independent)
__device__ __forceinline__ float lane_xor32(float v, bool pickx) {
    v2i r = __builtin_amdgcn_permlane32_swap(__float_as_int(v), __float_as_int(v),
                                             false, false);
    return __int_as_float(pickx ? r[0] : r[1]);
}

// ---------------------------------------------------------------------------
// GEMM: A[32000][K] x W[256][K]^T + (bi+bh), prescale by -log2e (g-rows:
// -2log2e) -> xpT[2*32][128][1000] (dir=1 time-reversed).
// 128m x 128n tile, 256 threads, 8x8 acc, BK=32.
// ---------------------------------------------------------------------------
__global__ __launch_bounds__(256)
void gemm_proj(const float* __restrict__ A, int K,
               const float* __restrict__ W,
               const float* __restrict__ bi,
               const float* __restrict__ bh,
               float* __restrict__ xpT)
{
    __shared__ __align__(16) float As[32][132];   // [k][m]
    __shared__ __align__(16) float Ws[32][132];   // [k][n]

    const int tid = threadIdx.x;
    const int m0 = blockIdx.x * 128;
    const int n0 = blockIdx.y * 128;
    const int tx = tid & 15;     // n-octet: n = n0 + tx*8 + ni
    const int ty = tid >> 4;     // m-octet: m = m0 + ty*8 + mi

    float acc[8][8] = {};

    const int row = tid >> 1;          // 0..127
    const int kq  = (tid & 1) * 16;    // 0 / 16

    const float* Ab = A + (size_t)(m0 + row) * K + kq;
    const float* Wb = W + (size_t)(n0 + row) * K + kq;

    float4 pa0 = *(const float4*)(Ab + 0);
    float4 pa1 = *(const float4*)(Ab + 4);
    float4 pa2 = *(const float4*)(Ab + 8);
    float4 pa3 = *(const float4*)(Ab + 12);
    float4 pw0 = *(const float4*)(Wb + 0);
    float4 pw1 = *(const float4*)(Wb + 4);
    float4 pw2 = *(const float4*)(Wb + 8);
    float4 pw3 = *(const float4*)(Wb + 12);

#define STAGE() do {                                                            \
        float av_[16] = {pa0.x,pa0.y,pa0.z,pa0.w, pa1.x,pa1.y,pa1.z,pa1.w,      \
                         pa2.x,pa2.y,pa2.z,pa2.w, pa3.x,pa3.y,pa3.z,pa3.w};     \
        float wv_[16] = {pw0.x,pw0.y,pw0.z,pw0.w, pw1.x,pw1.y,pw1.z,pw1.w,      \
                         pw2.x,pw2.y,pw2.z,pw2.w, pw3.x,pw3.y,pw3.z,pw3.w};     \
        _Pragma("unroll")                                                       \
        for (int q = 0; q < 16; ++q) As[kq + q][row] = av_[q];                  \
        _Pragma("unroll")                                                       \
        for (int q = 0; q < 16; ++q) Ws[kq + q][row] = wv_[q];                  \
    } while (0)

    STAGE();
    __syncthreads();

    const int nch = K >> 5;
    for (int ch = 0; ch < nch; ++ch) {
        const bool more = (ch + 1 < nch);
        if (more) {
            const int k0 = (ch + 1) * 32;
            pa0 = *(const float4*)(Ab + k0 + 0);
            pa1 = *(const float4*)(Ab + k0 + 4);
            pa2 = *(const float4*)(Ab + k0 + 8);
            pa3 = *(const float4*)(Ab + k0 + 12);
            pw0 = *(const float4*)(Wb + k0 + 0);
            pw1 = *(const float4*)(Wb + k0 + 4);
            pw2 = *(const float4*)(Wb + k0 + 8);
            pw3 = *(const float4*)(Wb + k0 + 12);
        }

#pragma unroll
        for (int kk = 0; kk < 32; ++kk) {
            float4 a0 = *(const float4*)&As[kk][ty * 8];
            float4 a1 = *(const float4*)&As[kk][ty * 8 + 4];
            float4 w0 = *(const float4*)&Ws[kk][tx * 8];
            float4 w1 = *(const float4*)&Ws[kk][tx * 8 + 4];
            float am[8] = {a0.x, a0.y, a0.z, a0.w, a1.x, a1.y, a1.z, a1.w};
            float wn[8] = {w0.x, w0.y, w0.z, w0.w, w1.x, w1.y, w1.z, w1.w};
#pragma unroll
            for (int mi = 0; mi < 8; ++mi)
#pragma unroll
                for (int ni = 0; ni < 8; ++ni)
                    acc[mi][ni] = fmaf(am[mi], wn[ni], acc[mi][ni]);
        }

        __syncthreads();
        if (more) {
            STAGE();
            __syncthreads();
        }
    }
#undef STAGE

    // epilogue: bias + prescale + transposed (dir=1 time-reversed) store
    const int dir = n0 >> 7;
    const int mb = m0 + ty * 8;
#pragma unroll
    for (int ni = 0; ni < 8; ++ni) {
        const int n = n0 + tx * 8 + ni;
        const float bias = bi[n] + bh[n];
        const float sc = (((n >> 5) & 3) == 2) ? (-2.0f * LOG2E) : (-LOG2E);
        float* rowp = xpT + ((size_t)((dir * 32) * 128) + (n & 127)) * TB;
#pragma unroll
        for (int qd = 0; qd < 2; ++qd) {
            const int mq = mb + qd * 4;
            const int bidx = mq / 1000;           // quad never crosses b (4|1000)
            const int ttq = mq - bidx * 1000;
            float* rp = rowp + (size_t)bidx * 128 * TB;
            if (dir == 0) {
                float4 o = {(acc[qd*4+0][ni] + bias) * sc,
                            (acc[qd*4+1][ni] + bias) * sc,
                            (acc[qd*4+2][ni] + bias) * sc,
                            (acc[qd*4+3][ni] + bias) * sc};
                *(float4*)(rp + ttq) = o;
            } else {
                float4 o = {(acc[qd*4+3][ni] + bias) * sc,
                            (acc[qd*4+2][ni] + bias) * sc,
                            (acc[qd*4+1][ni] + bias) * sc,
                            (acc[qd*4+0][ni] + bias) * sc};
                *(float4*)(rp + (TB - 4 - ttq)) = o;
            }
        }
    }
}

// ---------------------------------------------------------------------------
// Recurrence (round-10 verified): one wave per (dir,b). Lane l owns gate rows
// r0=(l&31)+(l>=32?64:0), r1=r0+32. h broadcast: ds_write_b32 + 8x
// ds_read_b128 with STAGED lgkmcnt waits. Gates prescaled: exp2 direct.
// ---------------------------------------------------------------------------
template<int MODE>
__global__ __launch_bounds__(64)
void lstm_rec(const float* __restrict__ xpT,  // [64][128][1000] prescaled
              const float* __restrict__ whh,  // [2][128][32]
              float* __restrict__ hout,       // [32][1000][64]
              float* __restrict__ hsum)       // [32][64]
{
    __shared__ __align__(16) float hsh[32];

    const int blk  = blockIdx.x;   // dir*32 + b
    const int dir  = blk >> 5;
    const int b    = blk & 31;
    const int lane = threadIdx.x & 63;
    const int j    = lane & 31;
    const int up   = lane >> 5;
    const int r0   = j + up * 64;
    const int r1   = r0 + 32;

    v2i det = __builtin_amdgcn_permlane32_swap(lane, lane, false, false);
    const bool pickx = (det[0] == (lane ^ 32));

    const float sA = up ? (-2.0f * LOG2E) : (-LOG2E);
    const float sB = -LOG2E;
    v2f wa[16], wb[16];
    {
        const float* wp0 = whh + (size_t)(dir * 128 + r0) * 32;
        const float* wp1 = whh + (size_t)(dir * 128 + r1) * 32;
#pragma unroll
        for (int q = 0; q < 8; ++q) {
            float4 v = *(const float4*)(wp0 + q * 4);
            wa[2 * q + 0][0] = v.x * sA; wa[2 * q + 0][1] = v.y * sA;
            wa[2 * q + 1][0] = v.z * sA; wa[2 * q + 1][1] = v.w * sA;
            float4 u = *(const float4*)(wp1 + q * 4);
            wb[2 * q + 0][0] = u.x * sB; wb[2 * q + 0][1] = u.y * sB;
            wb[2 * q + 1][0] = u.z * sB; wb[2 * q + 1][1] = u.w * sB;
        }
    }

    const float* pa = xpT + ((size_t)blk * 128 + r0) * TB;
    const float* pb = xpT + ((size_t)blk * 128 + r1) * TB;

    float4 A0 = *(const float4*)(pa + 0);
    float4 B0 = *(const float4*)(pb + 0);
    float4 A1 = *(const float4*)(pa + 4);
    float4 B1 = *(const float4*)(pb + 4);

    const float mA = up ?  2.0f : 1.0f;
    const float mB = up ? -1.0f : 0.0f;

    float c = 0.0f, h = 0.0f, hacc = 0.0f;
    float* hq = hout + ((size_t)b * TB + (dir ? TB - 1 : 0)) * 64 + dir * 32 + j;
    const int hstep = dir ? -64 : 64;

    const unsigned lds_z  = (unsigned)(size_t)&hsh[0];
    const unsigned lds_wa = lds_z + 4u * (unsigned)j;

    float4 hv0, hv1, hv2, hv3, hv4v, hv5, hv6, hv7;

#define DS_WRITE_H() \
    asm volatile("ds_write_b32 %0, %1" :: "v"(lds_wa), "v"(h))

#define DS_ISSUE_READS() do {                                                   \
    asm volatile("ds_read_b128 %0, %1 offset:0"   : "=v"(hv0)  : "v"(lds_z));   \
    asm volatile("ds_read_b128 %0, %1 offset:16"  : "=v"(hv1)  : "v"(lds_z));   \
    asm volatile("ds_read_b128 %0, %1 offset:32"  : "=v"(hv2)  : "v"(lds_z));   \
    asm volatile("ds_read_b128 %0, %1 offset:48"  : "=v"(hv3)  : "v"(lds_z));   \
    asm volatile("ds_read_b128 %0, %1 offset:64"  : "=v"(hv4v) : "v"(lds_z));   \
    asm volatile("ds_read_b128 %0, %1 offset:80"  : "=v"(hv5)  : "v"(lds_z));   \
    asm volatile("ds_read_b128 %0, %1 offset:96"  : "=v"(hv6)  : "v"(lds_z));   \
    asm volatile("ds_read_b128 %0, %1 offset:112" : "=v"(hv7)  : "v"(lds_z));   \
    } while (0)

#define MVG(HV, CNT, I0, I1, Q)                                                 \
    asm volatile("s_waitcnt lgkmcnt(" #CNT ")");                                \
    __builtin_amdgcn_sched_barrier(0);                                          \
    {                                                                           \
        v2f h0_ = {HV.x, HV.y};                                                 \
        v2f h1_ = {HV.z, HV.w};                                                 \
        qa[I0] = __builtin_elementwise_fma(h0_, wa[2*Q],   qa[I0]);             \
        qb[I0] = __builtin_elementwise_fma(h0_, wb[2*Q],   qb[I0]);             \
        qa[I1] = __builtin_elementwise_fma(h1_, wa[2*Q+1], qa[I1]);             \
        qb[I1] = __builtin_elementwise_fma(h1_, wb[2*Q+1], qb[I1]);             \
    }

    DS_WRITE_H();
    DS_ISSUE_READS();

#define LSTM_STEP(GA, GB) do {                                                  \
        v2f qa[4], qb[4];                                                       \
        qa[0] = v2f{(GA), 0.0f}; qa[1] = v2f{0.f, 0.f};                         \
        qa[2] = v2f{0.f, 0.f};   qa[3] = v2f{0.f, 0.f};                         \
        qb[0] = v2f{(GB), 0.0f}; qb[1] = v2f{0.f, 0.f};                         \
        qb[2] = v2f{0.f, 0.f};   qb[3] = v2f{0.f, 0.f};                         \
        MVG(hv0,  7, 0, 1, 0)                                                   \
        MVG(hv1,  6, 2, 3, 1)                                                   \
        MVG(hv2,  5, 0, 1, 2)                                                   \
        MVG(hv3,  4, 2, 3, 3)                                                   \
        MVG(hv4v, 3, 0, 1, 4)                                                   \
        MVG(hv5,  2, 2, 3, 5)                                                   \
        MVG(hv6,  1, 0, 1, 6)                                                   \
        MVG(hv7,  0, 2, 3, 7)                                                   \
        v2f sa = (qa[0] + qa[2]) + (qa[1] + qa[3]);                             \
        v2f sb = (qb[0] + qb[2]) + (qb[1] + qb[3]);                             \
        float g0 = sa[0] + sa[1];                                               \
        float g1 = sb[0] + sb[1];                                               \
        float s0 = __builtin_amdgcn_rcpf(1.0f + fexp2(g0));                     \
        float v0 = fmaf(mA, s0, mB);   /* lo: sig(i); hi: tanh(g) */            \
        float v1 = __builtin_amdgcn_rcpf(1.0f + fexp2(g1)); /* sig(f)/sig(o) */ \
        float o0 = lane_xor32(v0, pickx);                                       \
        float o1 = lane_xor32(v1, pickx);                                       \
        float P  = v0 * o0;            /* == si*tg in BOTH halves */            \
        float sf = up ? o1 : v1;                                                \
        float so = up ? v1 : o1;                                                \
        c = fmaf(sf, c, P);                                                     \
        float tc = fmaf(2.0f, __builtin_amdgcn_rcpf(1.0f + fexp2(c * (-2.0f * LOG2E))), -1.0f); \
        h = so * tc;                                                            \
        DS_WRITE_H();                                                           \
        DS_ISSUE_READS();                                                       \
        if (MODE == 0) {                                                        \
            asm volatile("global_store_dword %0, %1, off" :: "v"(hq), "v"(h));  \
        } else {                                                                \
            hacc += h;                                                          \
        }                                                                       \
        hq += hstep;                                                            \
    } while (0)

    for (int it = 0; it < 125; ++it) {
        const int base = it * 8;
        const int offn0 = min(base + 8,  TB - 4);   // clamped, unconditional
        const int offn1 = min(base + 12, TB - 4);
        float4 NA0 = *(const float4*)(pa + offn0);
        float4 NB0 = *(const float4*)(pb + offn0);
        float4 NA1 = *(const float4*)(pa + offn1);
        float4 NB1 = *(const float4*)(pb + offn1);

        LSTM_STEP(A0.x, B0.x);
        LSTM_STEP(A0.y, B0.y);
        LSTM_STEP(A0.z, B0.z);
        LSTM_STEP(A0.w, B0.w);
        LSTM_STEP(A1.x, B1.x);
        LSTM_STEP(A1.y, B1.y);
        LSTM_STEP(A1.z, B1.z);
        LSTM_STEP(A1.w, B1.w);

        A0 = NA0; B0 = NB0; A1 = NA1; B1 = NB1;
    }
#undef LSTM_STEP
#undef MVG
#undef DS_ISSUE_READS
#undef DS_WRITE_H

    asm volatile("s_waitcnt lgkmcnt(0)" ::: "memory");

    if (MODE == 1) hsum[b * 64 + dir * 32 + j] = hacc;
}

// ---------------------------------------------------------------------------
__global__ __launch_bounds__(64)
void final_fc(const float* __restrict__ hsum,
              const float* __restrict__ fcw,
              const float* __restrict__ fcb,
              float* __restrict__ out)
{
    int b = blockIdx.x;
    int l = threadIdx.x;
    float v = hsum[b * 64 + l] * (1.0f / (float)TB) * fcw[l];
#pragma unroll
    for (int off = 32; off > 0; off >>= 1)
        v += __shfl_down(v, off, 64);
    if (l == 0) out[b] = v + fcb[0];
}

// ---------------------------------------------------------------------------
extern "C" void kernel_launch(void* const* d_in, const int* in_sizes, int n_in,
                              void* d_out, int out_size, void* d_ws, size_t ws_size,
                              hipStream_t stream)
{
    const float* x    = (const float*)d_in[0];
    const float* wih0 = (const float*)d_in[1];
    const float* whh0 = (const float*)d_in[2];
    const float* bih0 = (const float*)d_in[3];
    const float* bhh0 = (const float*)d_in[4];
    const float* wih  = (const float*)d_in[5];
    const float* whh  = (const float*)d_in[6];
    const float* bih  = (const float*)d_in[7];
    const float* bhh  = (const float*)d_in[8];
    const float* fcw  = (const float*)d_in[9];
    const float* fcb  = (const float*)d_in[10];
    float* out = (float*)d_out;

    float* ws = (float*)d_ws;
    float* xp = ws;                         // 64*128*1000 floats
    float* hb = ws + 8192000;               // 32*1000*64 floats
    float* hs = ws + 8192000 + 2048000;     // 32*64

    dim3 gb(250, 2);

    gemm_proj<<<gb, 256, 0, stream>>>(x, 1024, wih0, bih0, bhh0, xp);
    lstm_rec<0><<<64, 64, 0, stream>>>(xp, whh0, hb, hs);

    for (int l = 1; l < 4; ++l) {
        const float* wl  = wih + (size_t)(l - 1) * 2 * 128 * 64;
        const float* whl = whh + (size_t)(l - 1) * 2 * 128 * 32;
        const float* b1  = bih + (size_t)(l - 1) * 256;
        const float* b2  = bhh + (size_t)(l - 1) * 256;
        gemm_proj<<<gb, 256, 0, stream>>>(hb, 64, wl, b1, b2, xp);
        if (l == 3) lstm_rec<1><<<64, 64, 0, stream>>>(xp, whl, hb, hs);
        else        lstm_rec<0><<<64, 64, 0, stream>>>(xp, whl, hb, hs);
    }

    final_fc<<<32, 64, 0, stream>>>(hs, fcw, fcb, out);
}

// Round 13
// 1207.277 us; speedup vs baseline: 1.7140x; 1.7140x over previous
//
#include <hip/hip_runtime.h>

// Wav2Vec BLSTM: 4-layer bi-LSTM (B=32, T=1000, H=32, G=128) + mean-pool + fc.
//
// Round 13: r10 GEMM structure (64x128 tile, acc[8][4], VGPR-lean) with ONE
// change: next chunk's global loads issued BEFORE computing current chunk
// (HBM latency hides under ~2000cy of fma). Single LDS buffer, order:
// {load next | compute cur | bar | write next | bar}.
// LSTM: round-10 verified (LDS broadcast + staged lgkmcnt waits).

#define TB 1000
#define LOG2E 1.44269504088896340736f

typedef int   v2i __attribute__((ext_vector_type(2)));
typedef float v2f __attribute__((ext_vector_type(2)));

__device__ __forceinline__ float fexp2(float x) {
#if __has_builtin(__builtin_amdgcn_exp2f)
    return __builtin_amdgcn_exp2f(x);
#else
    return exp2f(x);
#endif
}

// returns v[lane ^ 32]; pickx precomputed per-lane (convention-independent)
__device__ __forceinline__ float lane_xor32(float v, bool pickx) {
    v2i r = __builtin_amdgcn_permlane32_swap(__float_as_int(v), __float_as_int(v),
                                             false, false);
    return __int_as_float(pickx ? r[0] : r[1]);
}

// ---------------------------------------------------------------------------
// GEMM: A[32000][K] x W[256][K]^T + (bi+bh), prescale by -log2e (g-rows:
// -2log2e) -> xpT[2*32][128][1000] (dir=1 time-reversed).
// 64m x 128n tile, 256 threads, acc[8n][4m], BK=32, prefetch-next schedule.
// ---------------------------------------------------------------------------
__global__ __launch_bounds__(256)
void gemm_proj(const float* __restrict__ A, int K,
               const float* __restrict__ W,
               const float* __restrict__ bi,
               const float* __restrict__ bh,
               float* __restrict__ xpT)
{
    __shared__ __align__(16) float As[32][68];    // [k][m]
    __shared__ __align__(16) float Bs[32][132];   // [k][n]

    const int tid = threadIdx.x;
    const int m0 = blockIdx.x * 64;
    const int n0 = blockIdx.y * 128;
    const int tx = tid & 15;     // m-quad:  m = m0 + tx*4 + mj
    const int ty = tid >> 4;     // n-octet: n = n0 + ty*8 + ni

    float acc[8][4] = {};

    const int ar = tid >> 3;           // 0..31
    const int ak = (tid & 7) * 4;      // 0..28
    const int wr = tid >> 1;           // 0..127
    const int wk = (tid & 1) * 16;     // 0 / 16

    const float* Ab  = A + (size_t)(m0 + ar) * K + ak;
    const float* Ab2 = Ab + (size_t)32 * K;
    const float* Wb  = W + (size_t)(n0 + wr) * K + wk;

    float4 a0 = *(const float4*)(Ab);
    float4 a1 = *(const float4*)(Ab2);
    float4 w0 = *(const float4*)(Wb + 0);
    float4 w1 = *(const float4*)(Wb + 4);
    float4 w2 = *(const float4*)(Wb + 8);
    float4 w3 = *(const float4*)(Wb + 12);

#define STAGE() do {                                                            \
        As[ak + 0][ar] = a0.x; As[ak + 1][ar] = a0.y;                           \
        As[ak + 2][ar] = a0.z; As[ak + 3][ar] = a0.w;                           \
        As[ak + 0][ar + 32] = a1.x; As[ak + 1][ar + 32] = a1.y;                 \
        As[ak + 2][ar + 32] = a1.z; As[ak + 3][ar + 32] = a1.w;                 \
        float wv_[16] = {w0.x, w0.y, w0.z, w0.w, w1.x, w1.y, w1.z, w1.w,        \
                         w2.x, w2.y, w2.z, w2.w, w3.x, w3.y, w3.z, w3.w};       \
        _Pragma("unroll")                                                       \
        for (int q = 0; q < 16; ++q) Bs[wk + q][wr] = wv_[q];                   \
    } while (0)

    // prologue: stage chunk 0
    STAGE();
    __syncthreads();

    const int nch = K >> 5;
    for (int ch = 0; ch < nch; ++ch) {
        const bool more = (ch + 1 < nch);
        if (more) {
            const int k0 = (ch + 1) * 32;
            a0 = *(const float4*)(Ab + k0);
            a1 = *(const float4*)(Ab2 + k0);
            w0 = *(const float4*)(Wb + k0 + 0);
            w1 = *(const float4*)(Wb + k0 + 4);
            w2 = *(const float4*)(Wb + k0 + 8);
            w3 = *(const float4*)(Wb + k0 + 12);
        }

#pragma unroll
        for (int kk = 0; kk < 32; ++kk) {
            float4 av = *(const float4*)&As[kk][tx * 4];
            float4 b0 = *(const float4*)&Bs[kk][ty * 8];
            float4 b1 = *(const float4*)&Bs[kk][ty * 8 + 4];
            float bn[8] = {b0.x, b0.y, b0.z, b0.w, b1.x, b1.y, b1.z, b1.w};
#pragma unroll
            for (int ni = 0; ni < 8; ++ni) {
                acc[ni][0] = fmaf(av.x, bn[ni], acc[ni][0]);
                acc[ni][1] = fmaf(av.y, bn[ni], acc[ni][1]);
                acc[ni][2] = fmaf(av.z, bn[ni], acc[ni][2]);
                acc[ni][3] = fmaf(av.w, bn[ni], acc[ni][3]);
            }
        }

        __syncthreads();
        if (more) {
            STAGE();
            __syncthreads();
        }
    }
#undef STAGE

    // epilogue: bias + prescale + transposed (dir=1 time-reversed) store
    const int dir = n0 >> 7;
    const int mbase = m0 + tx * 4;
    const int bidx = mbase / 1000;        // quad never crosses b (4 | 1000)
    const int ttq = mbase - bidx * 1000;
#pragma unroll
    for (int ni = 0; ni < 8; ++ni) {
        const int n = n0 + ty * 8 + ni;
        const float bias = bi[n] + bh[n];
        const float sc = (((n >> 5) & 3) == 2) ? (-2.0f * LOG2E) : (-LOG2E);
        float* row = xpT + ((size_t)((dir * 32 + bidx) * 128) + (n & 127)) * TB;
        if (dir == 0) {
            float4 o = {(acc[ni][0] + bias) * sc, (acc[ni][1] + bias) * sc,
                        (acc[ni][2] + bias) * sc, (acc[ni][3] + bias) * sc};
            *(float4*)(row + ttq) = o;
        } else {
            float4 o = {(acc[ni][3] + bias) * sc, (acc[ni][2] + bias) * sc,
                        (acc[ni][1] + bias) * sc, (acc[ni][0] + bias) * sc};
            *(float4*)(row + (TB - 4 - ttq)) = o;
        }
    }
}

// ---------------------------------------------------------------------------
// Recurrence (round-10 verified): one wave per (dir,b). Lane l owns gate rows
// r0=(l&31)+(l>=32?64:0), r1=r0+32. h broadcast: ds_write_b32 + 8x
// ds_read_b128 with STAGED lgkmcnt waits. Gates prescaled: exp2 direct.
// ---------------------------------------------------------------------------
template<int MODE>
__global__ __launch_bounds__(64)
void lstm_rec(const float* __restrict__ xpT,  // [64][128][1000] prescaled
              const float* __restrict__ whh,  // [2][128][32]
              float* __restrict__ hout,       // [32][1000][64]
              float* __restrict__ hsum)       // [32][64]
{
    __shared__ __align__(16) float hsh[32];

    const int blk  = blockIdx.x;   // dir*32 + b
    const int dir  = blk >> 5;
    const int b    = blk & 31;
    const int lane = threadIdx.x & 63;
    const int j    = lane & 31;
    const int up   = lane >> 5;
    const int r0   = j + up * 64;
    const int r1   = r0 + 32;

    v2i det = __builtin_amdgcn_permlane32_swap(lane, lane, false, false);
    const bool pickx = (det[0] == (lane ^ 32));

    const float sA = up ? (-2.0f * LOG2E) : (-LOG2E);
    const float sB = -LOG2E;
    v2f wa[16], wb[16];
    {
        const float* wp0 = whh + (size_t)(dir * 128 + r0) * 32;
        const float* wp1 = whh + (size_t)(dir * 128 + r1) * 32;
#pragma unroll
        for (int q = 0; q < 8; ++q) {
            float4 v = *(const float4*)(wp0 + q * 4);
            wa[2 * q + 0][0] = v.x * sA; wa[2 * q + 0][1] = v.y * sA;
            wa[2 * q + 1][0] = v.z * sA; wa[2 * q + 1][1] = v.w * sA;
            float4 u = *(const float4*)(wp1 + q * 4);
            wb[2 * q + 0][0] = u.x * sB; wb[2 * q + 0][1] = u.y * sB;
            wb[2 * q + 1][0] = u.z * sB; wb[2 * q + 1][1] = u.w * sB;
        }
    }

    const float* pa = xpT + ((size_t)blk * 128 + r0) * TB;
    const float* pb = xpT + ((size_t)blk * 128 + r1) * TB;

    float4 A0 = *(const float4*)(pa + 0);
    float4 B0 = *(const float4*)(pb + 0);
    float4 A1 = *(const float4*)(pa + 4);
    float4 B1 = *(const float4*)(pb + 4);

    const float mA = up ?  2.0f : 1.0f;
    const float mB = up ? -1.0f : 0.0f;

    float c = 0.0f, h = 0.0f, hacc = 0.0f;
    float* hq = hout + ((size_t)b * TB + (dir ? TB - 1 : 0)) * 64 + dir * 32 + j;
    const int hstep = dir ? -64 : 64;

    const unsigned lds_z  = (unsigned)(size_t)&hsh[0];
    const unsigned lds_wa = lds_z + 4u * (unsigned)j;

    float4 hv0, hv1, hv2, hv3, hv4v, hv5, hv6, hv7;

#define DS_WRITE_H() \
    asm volatile("ds_write_b32 %0, %1" :: "v"(lds_wa), "v"(h))

#define DS_ISSUE_READS() do {                                                   \
    asm volatile("ds_read_b128 %0, %1 offset:0"   : "=v"(hv0)  : "v"(lds_z));   \
    asm volatile("ds_read_b128 %0, %1 offset:16"  : "=v"(hv1)  : "v"(lds_z));   \
    asm volatile("ds_read_b128 %0, %1 offset:32"  : "=v"(hv2)  : "v"(lds_z));   \
    asm volatile("ds_read_b128 %0, %1 offset:48"  : "=v"(hv3)  : "v"(lds_z));   \
    asm volatile("ds_read_b128 %0, %1 offset:64"  : "=v"(hv4v) : "v"(lds_z));   \
    asm volatile("ds_read_b128 %0, %1 offset:80"  : "=v"(hv5)  : "v"(lds_z));   \
    asm volatile("ds_read_b128 %0, %1 offset:96"  : "=v"(hv6)  : "v"(lds_z));   \
    asm volatile("ds_read_b128 %0, %1 offset:112" : "=v"(hv7)  : "v"(lds_z));   \
    } while (0)

#define MVG(HV, CNT, I0, I1, Q)                                                 \
    asm volatile("s_waitcnt lgkmcnt(" #CNT ")");                                \
    __builtin_amdgcn_sched_barrier(0);                                          \
    {                                                                           \
        v2f h0_ = {HV.x, HV.y};                                                 \
        v2f h1_ = {HV.z, HV.w};                                                 \
        qa[I0] = __builtin_elementwise_fma(h0_, wa[2*Q],   qa[I0]);             \
        qb[I0] = __builtin_elementwise_fma(h0_, wb[2*Q],   qb[I0]);             \
        qa[I1] = __builtin_elementwise_fma(h1_, wa[2*Q+1], qa[I1]);             \
        qb[I1] = __builtin_elementwise_fma(h1_, wb[2*Q+1], qb[I1]);             \
    }

    DS_WRITE_H();
    DS_ISSUE_READS();

#define LSTM_STEP(GA, GB) do {                                                  \
        v2f qa[4], qb[4];                                                       \
        qa[0] = v2f{(GA), 0.0f}; qa[1] = v2f{0.f, 0.f};                         \
        qa[2] = v2f{0.f, 0.f};   qa[3] = v2f{0.f, 0.f};                         \
        qb[0] = v2f{(GB), 0.0f}; qb[1] = v2f{0.f, 0.f};                         \
        qb[2] = v2f{0.f, 0.f};   qb[3] = v2f{0.f, 0.f};                         \
        MVG(hv0,  7, 0, 1, 0)                                                   \
        MVG(hv1,  6, 2, 3, 1)                                                   \
        MVG(hv2,  5, 0, 1, 2)                                                   \
        MVG(hv3,  4, 2, 3, 3)                                                   \
        MVG(hv4v, 3, 0, 1, 4)                                                   \
        MVG(hv5,  2, 2, 3, 5)                                                   \
        MVG(hv6,  1, 0, 1, 6)                                                   \
        MVG(hv7,  0, 2, 3, 7)                                                   \
        v2f sa = (qa[0] + qa[2]) + (qa[1] + qa[3]);                             \
        v2f sb = (qb[0] + qb[2]) + (qb[1] + qb[3]);                             \
        float g0 = sa[0] + sa[1];                                               \
        float g1 = sb[0] + sb[1];                                               \
        float s0 = __builtin_amdgcn_rcpf(1.0f + fexp2(g0));                     \
        float v0 = fmaf(mA, s0, mB);   /* lo: sig(i); hi: tanh(g) */            \
        float v1 = __builtin_amdgcn_rcpf(1.0f + fexp2(g1)); /* sig(f)/sig(o) */ \
        float o0 = lane_xor32(v0, pickx);                                       \
        float o1 = lane_xor32(v1, pickx);                                       \
        float P  = v0 * o0;            /* == si*tg in BOTH halves */            \
        float sf = up ? o1 : v1;                                                \
        float so = up ? v1 : o1;                                                \
        c = fmaf(sf, c, P);                                                     \
        float tc = fmaf(2.0f, __builtin_amdgcn_rcpf(1.0f + fexp2(c * (-2.0f * LOG2E))), -1.0f); \
        h = so * tc;                                                            \
        DS_WRITE_H();                                                           \
        DS_ISSUE_READS();                                                       \
        if (MODE == 0) {                                                        \
            asm volatile("global_store_dword %0, %1, off" :: "v"(hq), "v"(h));  \
        } else {                                                                \
            hacc += h;                                                          \
        }                                                                       \
        hq += hstep;                                                            \
    } while (0)

    for (int it = 0; it < 125; ++it) {
        const int base = it * 8;
        const int offn0 = min(base + 8,  TB - 4);   // clamped, unconditional
        const int offn1 = min(base + 12, TB - 4);
        float4 NA0 = *(const float4*)(pa + offn0);
        float4 NB0 = *(const float4*)(pb + offn0);
        float4 NA1 = *(const float4*)(pa + offn1);
        float4 NB1 = *(const float4*)(pb + offn1);

        LSTM_STEP(A0.x, B0.x);
        LSTM_STEP(A0.y, B0.y);
        LSTM_STEP(A0.z, B0.z);
        LSTM_STEP(A0.w, B0.w);
        LSTM_STEP(A1.x, B1.x);
        LSTM_STEP(A1.y, B1.y);
        LSTM_STEP(A1.z, B1.z);
        LSTM_STEP(A1.w, B1.w);

        A0 = NA0; B0 = NB0; A1 = NA1; B1 = NB1;
    }
#undef LSTM_STEP
#undef MVG
#undef DS_ISSUE_READS
#undef DS_WRITE_H

    asm volatile("s_waitcnt lgkmcnt(0)" ::: "memory");

    if (MODE == 1) hsum[b * 64 + dir * 32 + j] = hacc;
}

// ---------------------------------------------------------------------------
__global__ __launch_bounds__(64)
void final_fc(const float* __restrict__ hsum,
              const float* __restrict__ fcw,
              const float* __restrict__ fcb,
              float* __restrict__ out)
{
    int b = blockIdx.x;
    int l = threadIdx.x;
    float v = hsum[b * 64 + l] * (1.0f / (float)TB) * fcw[l];
#pragma unroll
    for (int off = 32; off > 0; off >>= 1)
        v += __shfl_down(v, off, 64);
    if (l == 0) out[b] = v + fcb[0];
}

// ---------------------------------------------------------------------------
extern "C" void kernel_launch(void* const* d_in, const int* in_sizes, int n_in,
                              void* d_out, int out_size, void* d_ws, size_t ws_size,
                              hipStream_t stream)
{
    const float* x    = (const float*)d_in[0];
    const float* wih0 = (const float*)d_in[1];
    const float* whh0 = (const float*)d_in[2];
    const float* bih0 = (const float*)d_in[3];
    const float* bhh0 = (const float*)d_in[4];
    const float* wih  = (const float*)d_in[5];
    const float* whh  = (const float*)d_in[6];
    const float* bih  = (const float*)d_in[7];
    const float* bhh  = (const float*)d_in[8];
    const float* fcw  = (const float*)d_in[9];
    const float* fcb  = (const float*)d_in[10];
    float* out = (float*)d_out;

    float* ws = (float*)d_ws;
    float* xp = ws;                         // 64*128*1000 floats
    float* hb = ws + 8192000;               // 32*1000*64 floats
    float* hs = ws + 8192000 + 2048000;     // 32*64

    dim3 gb(500, 2);

    gemm_proj<<<gb, 256, 0, stream>>>(x, 1024, wih0, bih0, bhh0, xp);
    lstm_rec<0><<<64, 64, 0, stream>>>(xp, whh0, hb, hs);

    for (int l = 1; l < 4; ++l) {
        const float* wl  = wih + (size_t)(l - 1) * 2 * 128 * 64;
        const float* whl = whh + (size_t)(l - 1) * 2 * 128 * 32;
        const float* b1  = bih + (size_t)(l - 1) * 256;
        const float* b2  = bhh + (size_t)(l - 1) * 256;
        gemm_proj<<<gb, 256, 0, stream>>>(hb, 64, wl, b1, b2, xp);
        if (l == 3) lstm_rec<1><<<64, 64, 0, stream>>>(xp, whl, hb, hs);
        else        lstm_rec<0><<<64, 64, 0, stream>>>(xp, whl, hb, hs);
    }

    final_fc<<<32, 64, 0, stream>>>(hs, fcw, fcb, out);
}

// Round 14
// 1203.864 us; speedup vs baseline: 1.7189x; 1.0028x over previous
//
#include <hip/hip_runtime.h>

// Wav2Vec BLSTM: 4-layer bi-LSTM (B=32, T=1000, H=32, G=128) + mean-pool + fc.
//
// Round 14:
//  GEMM = r13 (prefetch next chunk before compute) + sched_barrier(0) fence
//  between prefetch and the unrolled compute loop -> stops the scheduler
//  interleaving loads/waitcnts into the unroll (r13's VGPR 240 blowup).
//  LSTM = r10 verified structure + critical-chain micro-opts:
//    cs = -2log2e*c tracked directly (kills the on-chain mul before exp2);
//    h = fma(so+so, r, -so) (one dependent op after rcp instead of two).

#define TB 1000
#define LOG2E 1.44269504088896340736f

typedef int   v2i __attribute__((ext_vector_type(2)));
typedef float v2f __attribute__((ext_vector_type(2)));

__device__ __forceinline__ float fexp2(float x) {
#if __has_builtin(__builtin_amdgcn_exp2f)
    return __builtin_amdgcn_exp2f(x);
#else
    return exp2f(x);
#endif
}

// returns v[lane ^ 32]; pickx precomputed per-lane (convention-independent)
__device__ __forceinline__ float lane_xor32(float v, bool pickx) {
    v2i r = __builtin_amdgcn_permlane32_swap(__float_as_int(v), __float_as_int(v),
                                             false, false);
    return __int_as_float(pickx ? r[0] : r[1]);
}

// ---------------------------------------------------------------------------
// GEMM: A[32000][K] x W[256][K]^T + (bi+bh), prescale by -log2e (g-rows:
// -2log2e) -> xpT[2*32][128][1000] (dir=1 time-reversed).
// 64m x 128n tile, 256 threads, acc[8n][4m], BK=32.
// Schedule: {load next | FENCE | compute cur | bar | write next | bar}.
// ---------------------------------------------------------------------------
__global__ __launch_bounds__(256)
void gemm_proj(const float* __restrict__ A, int K,
               const float* __restrict__ W,
               const float* __restrict__ bi,
               const float* __restrict__ bh,
               float* __restrict__ xpT)
{
    __shared__ __align__(16) float As[32][68];    // [k][m]
    __shared__ __align__(16) float Bs[32][132];   // [k][n]

    const int tid = threadIdx.x;
    const int m0 = blockIdx.x * 64;
    const int n0 = blockIdx.y * 128;
    const int tx = tid & 15;     // m-quad:  m = m0 + tx*4 + mj
    const int ty = tid >> 4;     // n-octet: n = n0 + ty*8 + ni

    float acc[8][4] = {};

    const int ar = tid >> 3;           // 0..31
    const int ak = (tid & 7) * 4;      // 0..28
    const int wr = tid >> 1;           // 0..127
    const int wk = (tid & 1) * 16;     // 0 / 16

    const float* Ab  = A + (size_t)(m0 + ar) * K + ak;
    const float* Ab2 = Ab + (size_t)32 * K;
    const float* Wb  = W + (size_t)(n0 + wr) * K + wk;

    float4 a0 = *(const float4*)(Ab);
    float4 a1 = *(const float4*)(Ab2);
    float4 w0 = *(const float4*)(Wb + 0);
    float4 w1 = *(const float4*)(Wb + 4);
    float4 w2 = *(const float4*)(Wb + 8);
    float4 w3 = *(const float4*)(Wb + 12);

#define STAGE() do {                                                            \
        As[ak + 0][ar] = a0.x; As[ak + 1][ar] = a0.y;                           \
        As[ak + 2][ar] = a0.z; As[ak + 3][ar] = a0.w;                           \
        As[ak + 0][ar + 32] = a1.x; As[ak + 1][ar + 32] = a1.y;                 \
        As[ak + 2][ar + 32] = a1.z; As[ak + 3][ar + 32] = a1.w;                 \
        float wv_[16] = {w0.x, w0.y, w0.z, w0.w, w1.x, w1.y, w1.z, w1.w,        \
                         w2.x, w2.y, w2.z, w2.w, w3.x, w3.y, w3.z, w3.w};       \
        _Pragma("unroll")                                                       \
        for (int q = 0; q < 16; ++q) Bs[wk + q][wr] = wv_[q];                   \
    } while (0)

    // prologue: stage chunk 0
    STAGE();
    __syncthreads();

    const int nch = K >> 5;
    for (int ch = 0; ch < nch; ++ch) {
        const bool more = (ch + 1 < nch);
        if (more) {
            const int k0 = (ch + 1) * 32;
            a0 = *(const float4*)(Ab + k0);
            a1 = *(const float4*)(Ab2 + k0);
            w0 = *(const float4*)(Wb + k0 + 0);
            w1 = *(const float4*)(Wb + k0 + 4);
            w2 = *(const float4*)(Wb + k0 + 8);
            w3 = *(const float4*)(Wb + k0 + 12);
        }
        // FENCE: keep the prefetch loads (and their waitcnts) out of the
        // unrolled compute region -> no scheduler-driven register bloat.
        __builtin_amdgcn_sched_barrier(0);

#pragma unroll
        for (int kk = 0; kk < 32; ++kk) {
            float4 av = *(const float4*)&As[kk][tx * 4];
            float4 b0 = *(const float4*)&Bs[kk][ty * 8];
            float4 b1 = *(const float4*)&Bs[kk][ty * 8 + 4];
            float bn[8] = {b0.x, b0.y, b0.z, b0.w, b1.x, b1.y, b1.z, b1.w};
#pragma unroll
            for (int ni = 0; ni < 8; ++ni) {
                acc[ni][0] = fmaf(av.x, bn[ni], acc[ni][0]);
                acc[ni][1] = fmaf(av.y, bn[ni], acc[ni][1]);
                acc[ni][2] = fmaf(av.z, bn[ni], acc[ni][2]);
                acc[ni][3] = fmaf(av.w, bn[ni], acc[ni][3]);
            }
        }

        __builtin_amdgcn_sched_barrier(0);
        __syncthreads();
        if (more) {
            STAGE();
            __syncthreads();
        }
    }
#undef STAGE

    // epilogue: bias + prescale + transposed (dir=1 time-reversed) store
    const int dir = n0 >> 7;
    const int mbase = m0 + tx * 4;
    const int bidx = mbase / 1000;        // quad never crosses b (4 | 1000)
    const int ttq = mbase - bidx * 1000;
#pragma unroll
    for (int ni = 0; ni < 8; ++ni) {
        const int n = n0 + ty * 8 + ni;
        const float bias = bi[n] + bh[n];
        const float sc = (((n >> 5) & 3) == 2) ? (-2.0f * LOG2E) : (-LOG2E);
        float* row = xpT + ((size_t)((dir * 32 + bidx) * 128) + (n & 127)) * TB;
        if (dir == 0) {
            float4 o = {(acc[ni][0] + bias) * sc, (acc[ni][1] + bias) * sc,
                        (acc[ni][2] + bias) * sc, (acc[ni][3] + bias) * sc};
            *(float4*)(row + ttq) = o;
        } else {
            float4 o = {(acc[ni][3] + bias) * sc, (acc[ni][2] + bias) * sc,
                        (acc[ni][1] + bias) * sc, (acc[ni][0] + bias) * sc};
            *(float4*)(row + (TB - 4 - ttq)) = o;
        }
    }
}

// ---------------------------------------------------------------------------
// Recurrence (r10 verified + micro-opts): one wave per (dir,b). Lane l owns
// gate rows r0=(l&31)+(l>=32?64:0), r1=r0+32. h broadcast: ds_write_b32 +
// 8x ds_read_b128 with STAGED lgkmcnt waits. Gates prescaled: exp2 direct.
// cs = -2log2e * c tracked directly; h = fma(so+so, r, -so).
// ---------------------------------------------------------------------------
template<int MODE>
__global__ __launch_bounds__(64)
void lstm_rec(const float* __restrict__ xpT,  // [64][128][1000] prescaled
              const float* __restrict__ whh,  // [2][128][32]
              float* __restrict__ hout,       // [32][1000][64]
              float* __restrict__ hsum)       // [32][64]
{
    __shared__ __align__(16) float hsh[32];

    const int blk  = blockIdx.x;   // dir*32 + b
    const int dir  = blk >> 5;
    const int b    = blk & 31;
    const int lane = threadIdx.x & 63;
    const int j    = lane & 31;
    const int up   = lane >> 5;
    const int r0   = j + up * 64;
    const int r1   = r0 + 32;

    v2i det = __builtin_amdgcn_permlane32_swap(lane, lane, false, false);
    const bool pickx = (det[0] == (lane ^ 32));

    const float sA = up ? (-2.0f * LOG2E) : (-LOG2E);
    const float sB = -LOG2E;
    v2f wa[16], wb[16];
    {
        const float* wp0 = whh + (size_t)(dir * 128 + r0) * 32;
        const float* wp1 = whh + (size_t)(dir * 128 + r1) * 32;
#pragma unroll
        for (int q = 0; q < 8; ++q) {
            float4 v = *(const float4*)(wp0 + q * 4);
            wa[2 * q + 0][0] = v.x * sA; wa[2 * q + 0][1] = v.y * sA;
            wa[2 * q + 1][0] = v.z * sA; wa[2 * q + 1][1] = v.w * sA;
            float4 u = *(const float4*)(wp1 + q * 4);
            wb[2 * q + 0][0] = u.x * sB; wb[2 * q + 0][1] = u.y * sB;
            wb[2 * q + 1][0] = u.z * sB; wb[2 * q + 1][1] = u.w * sB;
        }
    }

    const float* pa = xpT + ((size_t)blk * 128 + r0) * TB;
    const float* pb = xpT + ((size_t)blk * 128 + r1) * TB;

    float4 A0 = *(const float4*)(pa + 0);
    float4 B0 = *(const float4*)(pb + 0);
    float4 A1 = *(const float4*)(pa + 4);
    float4 B1 = *(const float4*)(pb + 4);

    const float mA = up ?  2.0f : 1.0f;
    const float mB = up ? -1.0f : 0.0f;

    float cs = 0.0f, h = 0.0f, hacc = 0.0f;   // cs = -2log2e * c
    float* hq = hout + ((size_t)b * TB + (dir ? TB - 1 : 0)) * 64 + dir * 32 + j;
    const int hstep = dir ? -64 : 64;

    const unsigned lds_z  = (unsigned)(size_t)&hsh[0];
    const unsigned lds_wa = lds_z + 4u * (unsigned)j;

    float4 hv0, hv1, hv2, hv3, hv4v, hv5, hv6, hv7;

#define DS_WRITE_H() \
    asm volatile("ds_write_b32 %0, %1" :: "v"(lds_wa), "v"(h))

#define DS_ISSUE_READS() do {                                                   \
    asm volatile("ds_read_b128 %0, %1 offset:0"   : "=v"(hv0)  : "v"(lds_z));   \
    asm volatile("ds_read_b128 %0, %1 offset:16"  : "=v"(hv1)  : "v"(lds_z));   \
    asm volatile("ds_read_b128 %0, %1 offset:32"  : "=v"(hv2)  : "v"(lds_z));   \
    asm volatile("ds_read_b128 %0, %1 offset:48"  : "=v"(hv3)  : "v"(lds_z));   \
    asm volatile("ds_read_b128 %0, %1 offset:64"  : "=v"(hv4v) : "v"(lds_z));   \
    asm volatile("ds_read_b128 %0, %1 offset:80"  : "=v"(hv5)  : "v"(lds_z));   \
    asm volatile("ds_read_b128 %0, %1 offset:96"  : "=v"(hv6)  : "v"(lds_z));   \
    asm volatile("ds_read_b128 %0, %1 offset:112" : "=v"(hv7)  : "v"(lds_z));   \
    } while (0)

#define MVG(HV, CNT, I0, I1, Q)                                                 \
    asm volatile("s_waitcnt lgkmcnt(" #CNT ")");                                \
    __builtin_amdgcn_sched_barrier(0);                                          \
    {                                                                           \
        v2f h0_ = {HV.x, HV.y};                                                 \
        v2f h1_ = {HV.z, HV.w};                                                 \
        qa[I0] = __builtin_elementwise_fma(h0_, wa[2*Q],   qa[I0]);             \
        qb[I0] = __builtin_elementwise_fma(h0_, wb[2*Q],   qb[I0]);             \
        qa[I1] = __builtin_elementwise_fma(h1_, wa[2*Q+1], qa[I1]);             \
        qb[I1] = __builtin_elementwise_fma(h1_, wb[2*Q+1], qb[I1]);             \
    }

    DS_WRITE_H();
    DS_ISSUE_READS();

#define LSTM_STEP(GA, GB) do {                                                  \
        v2f qa[4], qb[4];                                                       \
        qa[0] = v2f{(GA), 0.0f}; qa[1] = v2f{0.f, 0.f};                         \
        qa[2] = v2f{0.f, 0.f};   qa[3] = v2f{0.f, 0.f};                         \
        qb[0] = v2f{(GB), 0.0f}; qb[1] = v2f{0.f, 0.f};                         \
        qb[2] = v2f{0.f, 0.f};   qb[3] = v2f{0.f, 0.f};                         \
        MVG(hv0,  7, 0, 1, 0)                                                   \
        MVG(hv1,  6, 2, 3, 1)                                                   \
        MVG(hv2,  5, 0, 1, 2)                                                   \
        MVG(hv3,  4, 2, 3, 3)                                                   \
        MVG(hv4v, 3, 0, 1, 4)                                                   \
        MVG(hv5,  2, 2, 3, 5)                                                   \
        MVG(hv6,  1, 0, 1, 6)                                                   \
        MVG(hv7,  0, 2, 3, 7)                                                   \
        v2f sa = (qa[0] + qa[2]) + (qa[1] + qa[3]);                             \
        v2f sb = (qb[0] + qb[2]) + (qb[1] + qb[3]);                             \
        float g0 = sa[0] + sa[1];                                               \
        float g1 = sb[0] + sb[1];                                               \
        float s0 = __builtin_amdgcn_rcpf(1.0f + fexp2(g0));                     \
        float v0 = fmaf(mA, s0, mB);   /* lo: sig(i); hi: tanh(g) */            \
        float v1 = __builtin_amdgcn_rcpf(1.0f + fexp2(g1)); /* sig(f)/sig(o) */ \
        float o0 = lane_xor32(v0, pickx);                                       \
        float o1 = lane_xor32(v1, pickx);                                       \
        float P  = v0 * o0;            /* == si*tg in BOTH halves */            \
        float Ps = P * (-2.0f * LOG2E);                                         \
        float sf = up ? o1 : v1;                                                \
        float so = up ? v1 : o1;                                                \
        cs = fmaf(sf, cs, Ps);         /* cs = -2log2e * c */                   \
        float r_ = __builtin_amdgcn_rcpf(1.0f + fexp2(cs));                     \
        float so2 = so + so;                                                    \
        h = fmaf(so2, r_, -so);        /* = so * tanh(c) */                     \
        DS_WRITE_H();                                                           \
        DS_ISSUE_READS();                                                       \
        if (MODE == 0) {                                                        \
            asm volatile("global_store_dword %0, %1, off" :: "v"(hq), "v"(h));  \
        } else {                                                                \
            hacc += h;                                                          \
        }                                                                       \
        hq += hstep;                                                            \
    } while (0)

    for (int it = 0; it < 125; ++it) {
        const int base = it * 8;
        const int offn0 = min(base + 8,  TB - 4);   // clamped, unconditional
        const int offn1 = min(base + 12, TB - 4);
        float4 NA0 = *(const float4*)(pa + offn0);
        float4 NB0 = *(const float4*)(pb + offn0);
        float4 NA1 = *(const float4*)(pa + offn1);
        float4 NB1 = *(const float4*)(pb + offn1);

        LSTM_STEP(A0.x, B0.x);
        LSTM_STEP(A0.y, B0.y);
        LSTM_STEP(A0.z, B0.z);
        LSTM_STEP(A0.w, B0.w);
        LSTM_STEP(A1.x, B1.x);
        LSTM_STEP(A1.y, B1.y);
        LSTM_STEP(A1.z, B1.z);
        LSTM_STEP(A1.w, B1.w);

        A0 = NA0; B0 = NB0; A1 = NA1; B1 = NB1;
    }
#undef LSTM_STEP
#undef MVG
#undef DS_ISSUE_READS
#undef DS_WRITE_H

    asm volatile("s_waitcnt lgkmcnt(0)" ::: "memory");

    if (MODE == 1) hsum[b * 64 + dir * 32 + j] = hacc;
}

// ---------------------------------------------------------------------------
__global__ __launch_bounds__(64)
void final_fc(const float* __restrict__ hsum,
              const float* __restrict__ fcw,
              const float* __restrict__ fcb,
              float* __restrict__ out)
{
    int b = blockIdx.x;
    int l = threadIdx.x;
    float v = hsum[b * 64 + l] * (1.0f / (float)TB) * fcw[l];
#pragma unroll
    for (int off = 32; off > 0; off >>= 1)
        v += __shfl_down(v, off, 64);
    if (l == 0) out[b] = v + fcb[0];
}

// ---------------------------------------------------------------------------
extern "C" void kernel_launch(void* const* d_in, const int* in_sizes, int n_in,
                              void* d_out, int out_size, void* d_ws, size_t ws_size,
                              hipStream_t stream)
{
    const float* x    = (const float*)d_in[0];
    const float* wih0 = (const float*)d_in[1];
    const float* whh0 = (const float*)d_in[2];
    const float* bih0 = (const float*)d_in[3];
    const float* bhh0 = (const float*)d_in[4];
    const float* wih  = (const float*)d_in[5];
    const float* whh  = (const float*)d_in[6];
    const float* bih  = (const float*)d_in[7];
    const float* bhh  = (const float*)d_in[8];
    const float* fcw  = (const float*)d_in[9];
    const float* fcb  = (const float*)d_in[10];
    float* out = (float*)d_out;

    float* ws = (float*)d_ws;
    float* xp = ws;                         // 64*128*1000 floats
    float* hb = ws + 8192000;               // 32*1000*64 floats
    float* hs = ws + 8192000 + 2048000;     // 32*64

    dim3 gb(500, 2);

    gemm_proj<<<gb, 256, 0, stream>>>(x, 1024, wih0, bih0, bhh0, xp);
    lstm_rec<0><<<64, 64, 0, stream>>>(xp, whh0, hb, hs);

    for (int l = 1; l < 4; ++l) {
        const float* wl  = wih + (size_t)(l - 1) * 2 * 128 * 64;
        const float* whl = whh + (size_t)(l - 1) * 2 * 128 * 32;
        const float* b1  = bih + (size_t)(l - 1) * 256;
        const float* b2  = bhh + (size_t)(l - 1) * 256;
        gemm_proj<<<gb, 256, 0, stream>>>(hb, 64, wl, b1, b2, xp);
        if (l == 3) lstm_rec<1><<<64, 64, 0, stream>>>(xp, whl, hb, hs);
        else        lstm_rec<0><<<64, 64, 0, stream>>>(xp, whl, hb, hs);
    }

    final_fc<<<32, 64, 0, stream>>>(hs, fcw, fcb, out);
}

// Round 15
// 1030.336 us; speedup vs baseline: 2.0084x; 1.1684x over previous
//
#include <hip/hip_runtime.h>

// Wav2Vec BLSTM: 4-layer bi-LSTM (B=32, T=1000, H=32, G=128) + mean-pool + fc.
//
// Round 15: consolidation. GEMM = exact r10 structure (44 VGPR, the only
// schedule that avoids the allocator blowup: load -> stage -> bar -> compute,
// loads never live across the unrolled compute). LSTM = r14 (r10 verified
// broadcast + staged lgkmcnt waits + cs/h chain folding). No experiments.

#define TB 1000
#define LOG2E 1.44269504088896340736f

typedef int   v2i __attribute__((ext_vector_type(2)));
typedef float v2f __attribute__((ext_vector_type(2)));

__device__ __forceinline__ float fexp2(float x) {
#if __has_builtin(__builtin_amdgcn_exp2f)
    return __builtin_amdgcn_exp2f(x);
#else
    return exp2f(x);
#endif
}

// returns v[lane ^ 32]; pickx precomputed per-lane (convention-independent)
__device__ __forceinline__ float lane_xor32(float v, bool pickx) {
    v2i r = __builtin_amdgcn_permlane32_swap(__float_as_int(v), __float_as_int(v),
                                             false, false);
    return __int_as_float(pickx ? r[0] : r[1]);
}

// ---------------------------------------------------------------------------
// GEMM (r10): A[32000][K] x W[256][K]^T + (bi+bh), prescale by -log2e
// (g-rows: -2log2e) -> xpT[2*32][128][1000] (dir=1 time-reversed).
// 64m x 128n tile, 256 threads, acc[8n][4m], BK=32.
// ---------------------------------------------------------------------------
__global__ __launch_bounds__(256)
void gemm_proj(const float* __restrict__ A, int K,
               const float* __restrict__ W,
               const float* __restrict__ bi,
               const float* __restrict__ bh,
               float* __restrict__ xpT)
{
    __shared__ __align__(16) float As[32][68];    // [k][m]
    __shared__ __align__(16) float Bs[32][132];   // [k][n]

    const int tid = threadIdx.x;
    const int m0 = blockIdx.x * 64;
    const int n0 = blockIdx.y * 128;
    const int tx = tid & 15;     // m-quad:  m = m0 + tx*4 + mj
    const int ty = tid >> 4;     // n-octet: n = n0 + ty*8 + ni

    float acc[8][4];
#pragma unroll
    for (int i = 0; i < 8; ++i)
#pragma unroll
        for (int jj = 0; jj < 4; ++jj) acc[i][jj] = 0.0f;

    const int ar = tid >> 3;           // 0..31
    const int ak = (tid & 7) * 4;      // 0..28
    const int wr = tid >> 1;           // 0..127
    const int wk = (tid & 1) * 16;     // 0 / 16

    for (int k0 = 0; k0 < K; k0 += 32) {
        float4 a0 = *(const float4*)(A + (size_t)(m0 + ar) * K + k0 + ak);
        float4 a1 = *(const float4*)(A + (size_t)(m0 + ar + 32) * K + k0 + ak);
        const float* wp = W + (size_t)(n0 + wr) * K + k0 + wk;
        float4 w0 = *(const float4*)(wp + 0);
        float4 w1 = *(const float4*)(wp + 4);
        float4 w2 = *(const float4*)(wp + 8);
        float4 w3 = *(const float4*)(wp + 12);

        __syncthreads();
        As[ak + 0][ar] = a0.x; As[ak + 1][ar] = a0.y;
        As[ak + 2][ar] = a0.z; As[ak + 3][ar] = a0.w;
        As[ak + 0][ar + 32] = a1.x; As[ak + 1][ar + 32] = a1.y;
        As[ak + 2][ar + 32] = a1.z; As[ak + 3][ar + 32] = a1.w;
        {
            float wv[16] = {w0.x, w0.y, w0.z, w0.w,
                            w1.x, w1.y, w1.z, w1.w,
                            w2.x, w2.y, w2.z, w2.w,
                            w3.x, w3.y, w3.z, w3.w};
#pragma unroll
            for (int q = 0; q < 16; ++q) Bs[wk + q][wr] = wv[q];
        }
        __syncthreads();

#pragma unroll
        for (int kk = 0; kk < 32; ++kk) {
            float4 av = *(const float4*)&As[kk][tx * 4];
            float4 b0 = *(const float4*)&Bs[kk][ty * 8];
            float4 b1 = *(const float4*)&Bs[kk][ty * 8 + 4];
            float bn[8] = {b0.x, b0.y, b0.z, b0.w, b1.x, b1.y, b1.z, b1.w};
#pragma unroll
            for (int ni = 0; ni < 8; ++ni) {
                acc[ni][0] = fmaf(av.x, bn[ni], acc[ni][0]);
                acc[ni][1] = fmaf(av.y, bn[ni], acc[ni][1]);
                acc[ni][2] = fmaf(av.z, bn[ni], acc[ni][2]);
                acc[ni][3] = fmaf(av.w, bn[ni], acc[ni][3]);
            }
        }
    }

    // epilogue: bias + prescale + transposed (dir=1 time-reversed) store
    const int dir = n0 >> 7;
    const int mbase = m0 + tx * 4;
    const int bidx = mbase / 1000;        // quad never crosses b (4 | 1000)
    const int ttq = mbase - bidx * 1000;
#pragma unroll
    for (int ni = 0; ni < 8; ++ni) {
        const int n = n0 + ty * 8 + ni;
        const float bias = bi[n] + bh[n];
        const float sc = (((n >> 5) & 3) == 2) ? (-2.0f * LOG2E) : (-LOG2E);
        float* row = xpT + ((size_t)((dir * 32 + bidx) * 128) + (n & 127)) * TB;
        if (dir == 0) {
            float4 o = {(acc[ni][0] + bias) * sc, (acc[ni][1] + bias) * sc,
                        (acc[ni][2] + bias) * sc, (acc[ni][3] + bias) * sc};
            *(float4*)(row + ttq) = o;
        } else {
            float4 o = {(acc[ni][3] + bias) * sc, (acc[ni][2] + bias) * sc,
                        (acc[ni][1] + bias) * sc, (acc[ni][0] + bias) * sc};
            *(float4*)(row + (TB - 4 - ttq)) = o;
        }
    }
}

// ---------------------------------------------------------------------------
// Recurrence (r14): one wave per (dir,b). Lane l owns gate rows
// r0=(l&31)+(l>=32?64:0), r1=r0+32. h broadcast: ds_write_b32 + 8x
// ds_read_b128 with STAGED lgkmcnt waits. Gates prescaled: exp2 direct.
// cs = -2log2e * c tracked directly; h = fma(so+so, r, -so).
// ---------------------------------------------------------------------------
template<int MODE>
__global__ __launch_bounds__(64)
void lstm_rec(const float* __restrict__ xpT,  // [64][128][1000] prescaled
              const float* __restrict__ whh,  // [2][128][32]
              float* __restrict__ hout,       // [32][1000][64]
              float* __restrict__ hsum)       // [32][64]
{
    __shared__ __align__(16) float hsh[32];

    const int blk  = blockIdx.x;   // dir*32 + b
    const int dir  = blk >> 5;
    const int b    = blk & 31;
    const int lane = threadIdx.x & 63;
    const int j    = lane & 31;
    const int up   = lane >> 5;
    const int r0   = j + up * 64;
    const int r1   = r0 + 32;

    v2i det = __builtin_amdgcn_permlane32_swap(lane, lane, false, false);
    const bool pickx = (det[0] == (lane ^ 32));

    const float sA = up ? (-2.0f * LOG2E) : (-LOG2E);
    const float sB = -LOG2E;
    v2f wa[16], wb[16];
    {
        const float* wp0 = whh + (size_t)(dir * 128 + r0) * 32;
        const float* wp1 = whh + (size_t)(dir * 128 + r1) * 32;
#pragma unroll
        for (int q = 0; q < 8; ++q) {
            float4 v = *(const float4*)(wp0 + q * 4);
            wa[2 * q + 0][0] = v.x * sA; wa[2 * q + 0][1] = v.y * sA;
            wa[2 * q + 1][0] = v.z * sA; wa[2 * q + 1][1] = v.w * sA;
            float4 u = *(const float4*)(wp1 + q * 4);
            wb[2 * q + 0][0] = u.x * sB; wb[2 * q + 0][1] = u.y * sB;
            wb[2 * q + 1][0] = u.z * sB; wb[2 * q + 1][1] = u.w * sB;
        }
    }

    const float* pa = xpT + ((size_t)blk * 128 + r0) * TB;
    const float* pb = xpT + ((size_t)blk * 128 + r1) * TB;

    float4 A0 = *(const float4*)(pa + 0);
    float4 B0 = *(const float4*)(pb + 0);
    float4 A1 = *(const float4*)(pa + 4);
    float4 B1 = *(const float4*)(pb + 4);

    const float mA = up ?  2.0f : 1.0f;
    const float mB = up ? -1.0f : 0.0f;

    float cs = 0.0f, h = 0.0f, hacc = 0.0f;   // cs = -2log2e * c
    float* hq = hout + ((size_t)b * TB + (dir ? TB - 1 : 0)) * 64 + dir * 32 + j;
    const int hstep = dir ? -64 : 64;

    const unsigned lds_z  = (unsigned)(size_t)&hsh[0];
    const unsigned lds_wa = lds_z + 4u * (unsigned)j;

    float4 hv0, hv1, hv2, hv3, hv4v, hv5, hv6, hv7;

#define DS_WRITE_H() \
    asm volatile("ds_write_b32 %0, %1" :: "v"(lds_wa), "v"(h))

#define DS_ISSUE_READS() do {                                                   \
    asm volatile("ds_read_b128 %0, %1 offset:0"   : "=v"(hv0)  : "v"(lds_z));   \
    asm volatile("ds_read_b128 %0, %1 offset:16"  : "=v"(hv1)  : "v"(lds_z));   \
    asm volatile("ds_read_b128 %0, %1 offset:32"  : "=v"(hv2)  : "v"(lds_z));   \
    asm volatile("ds_read_b128 %0, %1 offset:48"  : "=v"(hv3)  : "v"(lds_z));   \
    asm volatile("ds_read_b128 %0, %1 offset:64"  : "=v"(hv4v) : "v"(lds_z));   \
    asm volatile("ds_read_b128 %0, %1 offset:80"  : "=v"(hv5)  : "v"(lds_z));   \
    asm volatile("ds_read_b128 %0, %1 offset:96"  : "=v"(hv6)  : "v"(lds_z));   \
    asm volatile("ds_read_b128 %0, %1 offset:112" : "=v"(hv7)  : "v"(lds_z));   \
    } while (0)

#define MVG(HV, CNT, I0, I1, Q)                                                 \
    asm volatile("s_waitcnt lgkmcnt(" #CNT ")");                                \
    __builtin_amdgcn_sched_barrier(0);                                          \
    {                                                                           \
        v2f h0_ = {HV.x, HV.y};                                                 \
        v2f h1_ = {HV.z, HV.w};                                                 \
        qa[I0] = __builtin_elementwise_fma(h0_, wa[2*Q],   qa[I0]);             \
        qb[I0] = __builtin_elementwise_fma(h0_, wb[2*Q],   qb[I0]);             \
        qa[I1] = __builtin_elementwise_fma(h1_, wa[2*Q+1], qa[I1]);             \
        qb[I1] = __builtin_elementwise_fma(h1_, wb[2*Q+1], qb[I1]);             \
    }

    DS_WRITE_H();
    DS_ISSUE_READS();

#define LSTM_STEP(GA, GB) do {                                                  \
        v2f qa[4], qb[4];                                                       \
        qa[0] = v2f{(GA), 0.0f}; qa[1] = v2f{0.f, 0.f};                         \
        qa[2] = v2f{0.f, 0.f};   qa[3] = v2f{0.f, 0.f};                         \
        qb[0] = v2f{(GB), 0.0f}; qb[1] = v2f{0.f, 0.f};                         \
        qb[2] = v2f{0.f, 0.f};   qb[3] = v2f{0.f, 0.f};                         \
        MVG(hv0,  7, 0, 1, 0)                                                   \
        MVG(hv1,  6, 2, 3, 1)                                                   \
        MVG(hv2,  5, 0, 1, 2)                                                   \
        MVG(hv3,  4, 2, 3, 3)                                                   \
        MVG(hv4v, 3, 0, 1, 4)                                                   \
        MVG(hv5,  2, 2, 3, 5)                                                   \
        MVG(hv6,  1, 0, 1, 6)                                                   \
        MVG(hv7,  0, 2, 3, 7)                                                   \
        v2f sa = (qa[0] + qa[2]) + (qa[1] + qa[3]);                             \
        v2f sb = (qb[0] + qb[2]) + (qb[1] + qb[3]);                             \
        float g0 = sa[0] + sa[1];                                               \
        float g1 = sb[0] + sb[1];                                               \
        float s0 = __builtin_amdgcn_rcpf(1.0f + fexp2(g0));                     \
        float v0 = fmaf(mA, s0, mB);   /* lo: sig(i); hi: tanh(g) */            \
        float v1 = __builtin_amdgcn_rcpf(1.0f + fexp2(g1)); /* sig(f)/sig(o) */ \
        float o0 = lane_xor32(v0, pickx);                                       \
        float o1 = lane_xor32(v1, pickx);                                       \
        float P  = v0 * o0;            /* == si*tg in BOTH halves */            \
        float Ps = P * (-2.0f * LOG2E);                                         \
        float sf = up ? o1 : v1;                                                \
        float so = up ? v1 : o1;                                                \
        cs = fmaf(sf, cs, Ps);         /* cs = -2log2e * c */                   \
        float r_ = __builtin_amdgcn_rcpf(1.0f + fexp2(cs));                     \
        float so2 = so + so;                                                    \
        h = fmaf(so2, r_, -so);        /* = so * tanh(c) */                     \
        DS_WRITE_H();                                                           \
        DS_ISSUE_READS();                                                       \
        if (MODE == 0) {                                                        \
            asm volatile("global_store_dword %0, %1, off" :: "v"(hq), "v"(h));  \
        } else {                                                                \
            hacc += h;                                                          \
        }                                                                       \
        hq += hstep;                                                            \
    } while (0)

    for (int it = 0; it < 125; ++it) {
        const int base = it * 8;
        const int offn0 = min(base + 8,  TB - 4);   // clamped, unconditional
        const int offn1 = min(base + 12, TB - 4);
        float4 NA0 = *(const float4*)(pa + offn0);
        float4 NB0 = *(const float4*)(pb + offn0);
        float4 NA1 = *(const float4*)(pa + offn1);
        float4 NB1 = *(const float4*)(pb + offn1);

        LSTM_STEP(A0.x, B0.x);
        LSTM_STEP(A0.y, B0.y);
        LSTM_STEP(A0.z, B0.z);
        LSTM_STEP(A0.w, B0.w);
        LSTM_STEP(A1.x, B1.x);
        LSTM_STEP(A1.y, B1.y);
        LSTM_STEP(A1.z, B1.z);
        LSTM_STEP(A1.w, B1.w);

        A0 = NA0; B0 = NB0; A1 = NA1; B1 = NB1;
    }
#undef LSTM_STEP
#undef MVG
#undef DS_ISSUE_READS
#undef DS_WRITE_H

    asm volatile("s_waitcnt lgkmcnt(0)" ::: "memory");

    if (MODE == 1) hsum[b * 64 + dir * 32 + j] = hacc;
}

// ---------------------------------------------------------------------------
__global__ __launch_bounds__(64)
void final_fc(const float* __restrict__ hsum,
              const float* __restrict__ fcw,
              const float* __restrict__ fcb,
              float* __restrict__ out)
{
    int b = blockIdx.x;
    int l = threadIdx.x;
    float v = hsum[b * 64 + l] * (1.0f / (float)TB) * fcw[l];
#pragma unroll
    for (int off = 32; off > 0; off >>= 1)
        v += __shfl_down(v, off, 64);
    if (l == 0) out[b] = v + fcb[0];
}

// ---------------------------------------------------------------------------
extern "C" void kernel_launch(void* const* d_in, const int* in_sizes, int n_in,
                              void* d_out, int out_size, void* d_ws, size_t ws_size,
                              hipStream_t stream)
{
    const float* x    = (const float*)d_in[0];
    const float* wih0 = (const float*)d_in[1];
    const float* whh0 = (const float*)d_in[2];
    const float* bih0 = (const float*)d_in[3];
    const float* bhh0 = (const float*)d_in[4];
    const float* wih  = (const float*)d_in[5];
    const float* whh  = (const float*)d_in[6];
    const float* bih  = (const float*)d_in[7];
    const float* bhh  = (const float*)d_in[8];
    const float* fcw  = (const float*)d_in[9];
    const float* fcb  = (const float*)d_in[10];
    float* out = (float*)d_out;

    float* ws = (float*)d_ws;
    float* xp = ws;                         // 64*128*1000 floats
    float* hb = ws + 8192000;               // 32*1000*64 floats
    float* hs = ws + 8192000 + 2048000;     // 32*64

    dim3 gb(500, 2);

    gemm_proj<<<gb, 256, 0, stream>>>(x, 1024, wih0, bih0, bhh0, xp);
    lstm_rec<0><<<64, 64, 0, stream>>>(xp, whh0, hb, hs);

    for (int l = 1; l < 4; ++l) {
        const float* wl  = wih + (size_t)(l - 1) * 2 * 128 * 64;
        const float* whl = whh + (size_t)(l - 1) * 2 * 128 * 32;
        const float* b1  = bih + (size_t)(l - 1) * 256;
        const float* b2  = bhh + (size_t)(l - 1) * 256;
        gemm_proj<<<gb, 256, 0, stream>>>(hb, 64, wl, b1, b2, xp);
        if (l == 3) lstm_rec<1><<<64, 64, 0, stream>>>(xp, whl, hb, hs);
        else        lstm_rec<0><<<64, 64, 0, stream>>>(xp, whl, hb, hs);
    }

    final_fc<<<32, 64, 0, stream>>>(hs, fcw, fcb, out);
}